// Round 18
// baseline (568.706 us; speedup 1.0000x reference)
//
#include <hip/hip_runtime.h>

#define T_STEPS 512
#define B_ENV   256
#define D_IN    64
#define H_DIM   128
#define G4      512   // 4*H gate rows

typedef _Float16 h2v __attribute__((ext_vector_type(2)));
typedef _Float16 h8v __attribute__((ext_vector_type(8)));
typedef float    f4v __attribute__((ext_vector_type(4)));
typedef __fp16   g2  __attribute__((ext_vector_type(2)));
typedef __fp16   g8  __attribute__((ext_vector_type(8)));

__device__ __forceinline__ float dot2(h2v a, h2v b, float c) {
#if __has_builtin(__builtin_amdgcn_fdot2)
    return __builtin_amdgcn_fdot2(a, b, c, false);
#else
    return c + (float)a.x * (float)b.x + (float)a.y * (float)b.y;
#endif
}

__device__ __forceinline__ g2 pack16g(float a, float b) {
#if __has_builtin(__builtin_amdgcn_cvt_pkrtz)
    return __builtin_amdgcn_cvt_pkrtz(a, b);
#else
    g2 p; p.x = (__fp16)a; p.y = (__fp16)b; return p;
#endif
}
__device__ __forceinline__ h2v pack16(float a, float b) {
    union { g2 r; h2v h; } u; u.r = pack16g(a, b); return u.h;
}

__device__ __forceinline__ f4v mfma16(g8 a, g8 b, f4v c) {
    return __builtin_amdgcn_mfma_f32_16x16x32_f16(a, b, c, 0, 0, 0);
}

__device__ __forceinline__ float fast_rcp(float x) {
#if __has_builtin(__builtin_amdgcn_rcpf)
    return __builtin_amdgcn_rcpf(x);
#else
    return 1.0f / x;
#endif
}
__device__ __forceinline__ float sigm(float x)   { return fast_rcp(1.0f + __expf(-x)); }
__device__ __forceinline__ float tanh_f(float x) { float e = __expf(2.0f * x); return 1.0f - 2.0f * fast_rcp(e + 1.0f); }

// DPP quad_perm ops (VALU pipe — never LDS).
template <int CTRL>
__device__ __forceinline__ float dpp_mov(float v) {
    int s = __builtin_amdgcn_update_dpp(
        0, __builtin_bit_cast(int, v), CTRL, 0xF, 0xF, true);
    return __builtin_bit_cast(float, s);
}
__device__ __forceinline__ float quad_allreduce(float v) {
    v += dpp_mov<0xB1>(v);   // quad_perm(1,0,3,2): xor1
    v += dpp_mov<0x4E>(v);   // quad_perm(2,3,0,1): xor2
    return v;
}

// Barrier draining LDS ops only — global loads/stores stay in flight.
__device__ __forceinline__ void sync_lds() {
    asm volatile("s_waitcnt lgkmcnt(0)" ::: "memory");
    __builtin_amdgcn_s_barrier();
    asm volatile("" ::: "memory");
}

// ---------------------------------------------------------------------------
// xg GEMM: xg[tb, r] = x[tb,:] . W_ih[r,:] + b_ih[r] + b_hh[r]  (f16 out).
// Bias folded in via MFMA acc-init. M = T*B (2048 blocks x 64), N=512, K=64.
__global__ __launch_bounds__(256)
void ppo_xg(const float* __restrict__ x,     // [T*B, 64]
            const float* __restrict__ W_ih,  // [512, 64]
            const float* __restrict__ b_ih,  // [512]
            const float* __restrict__ b_hh,  // [512]
            unsigned short* __restrict__ xg) // [T*B, 512] f16 bits
{
    const int tid  = threadIdx.x;
    const int lane = tid & 63;
    const int w    = tid >> 6;
    const int rml  = lane & 15;
    const int colg = lane >> 4;

    __shared__ h2v   wl[G4][36];   // 512 rows x 32 h2v (+4 pad) = 72 KB
    __shared__ float bl[G4];       // bias per gate row (2 KB)

    #pragma unroll
    for (int i = 0; i < 32; ++i) {             // stage W_ih: 8192 f4v
        const int idx = tid + 256 * i;
        const int r = idx >> 4, cc = idx & 15;
        f4v v = *reinterpret_cast<const f4v*>(W_ih + (size_t)idx * 4);
        wl[r][2 * cc]     = pack16(v.x, v.y);
        wl[r][2 * cc + 1] = pack16(v.z, v.w);
    }
    bl[tid]       = b_ih[tid]       + b_hh[tid];
    bl[tid + 256] = b_ih[tid + 256] + b_hh[tid + 256];
    __syncthreads();

    const size_t row0 = (size_t)blockIdx.x * 64 + w * 16;

    // A-frags: 2 K-strips of x rows (lane rml = row, colg = k-group)
    g8 a[2];
    #pragma unroll
    for (int ks = 0; ks < 2; ++ks) {
        const float* p = x + (row0 + rml) * D_IN + ks * 32 + colg * 8;
        union { g2 q[4]; g8 v; } u;
        #pragma unroll
        for (int c = 0; c < 4; ++c) u.q[c] = pack16g(p[2 * c], p[2 * c + 1]);
        a[ks] = u.v;
    }

    #pragma unroll 4
    for (int ct = 0; ct < 32; ++ct) {          // 32 column tiles of 16 gates
        const int col = ct * 16 + rml;         // B col = lane&15 = C col
        const g8 b0 = *reinterpret_cast<const g8*>(&wl[col][colg * 4]);
        const g8 b1 = *reinterpret_cast<const g8*>(&wl[col][16 + colg * 4]);
        const float bb = bl[col];
        f4v acc = {bb, bb, bb, bb};
        acc = mfma16(a[0], b0, acc);
        acc = mfma16(a[1], b1, acc);
        // C: row = colg*4+reg, col = rml
        #pragma unroll
        for (int reg = 0; reg < 4; ++reg) {
            const __fp16 hv = (__fp16)acc[reg];
            xg[(row0 + colg * 4 + reg) * G4 + ct * 16 + rml] =
                __builtin_bit_cast(unsigned short, hv);
        }
    }
}

// ---------------------------------------------------------------------------
// TLP scan: TWO envs per 1024-thread block (grid 128, one block per CU,
// 16 waves = 4 waves/SIMD). Waves 0-7 run env blockIdx*2, waves 8-15 env
// blockIdx*2+1 — two independent R15-body recurrences sharing only the
// block barrier. Env A's dep-chain stalls (ds_read latency, DPP deps,
// trans ops, barrier resume) are filled by env B's issue on the same SIMD.
// REGISTER PRESSURE: this scan needs only ~68-80 VGPRs (weights = whh[64],
// bias folded into xg by ppo_xg) — unlike R10-12's 150-reg kernel, it fits
// the 1024-block budget. waves_per_eu(4,4) pins exactly 4/EU (cap 128).
// Per-env structure = R15 loop body verbatim (quad allreduce + lane-
// specialized activation + 4 DPP broadcasts — R16/R17 variants were worse),
// minus the bias add (pre-folded into xg).
__global__ __attribute__((amdgpu_flat_work_group_size(1024, 1024),
                          amdgpu_waves_per_eu(4, 4)))
void ppo_lstm_scan_xg2(const unsigned short* __restrict__ xg,  // [T,B,4H] f16
                       const float* __restrict__ done,   // [T,B]
                       const float* __restrict__ h0,     // [B,H]
                       const float* __restrict__ c0,     // [B,H]
                       const float* __restrict__ W_hh,   // [4H,H]
                       float* __restrict__ hs)           // [T,B,H] = d_out
{
    const int tid  = threadIdx.x;
    const int half = tid >> 9;           // env within block
    const int l    = tid & 511;          // local tid within env
    const int b    = blockIdx.x * 2 + half;
    const int qq   = l & 3;
    const int j    = l >> 2;

    __shared__ alignas(16) h2v   h16[2][2][H_DIM / 2]; // [half][dbuf][..]
    __shared__ alignas(16) float smask[2][T_STEPS];

    h2v whh[64];   // gate g, k-quarter qq: 16 h2v each
    #pragma unroll
    for (int g = 0; g < 4; ++g) {
        const float* wr = W_hh + (size_t)(g * H_DIM + j) * H_DIM + qq * 32;
        #pragma unroll
        for (int c = 0; c < 16; ++c)
            whh[g * 16 + c] = pack16(wr[2 * c], wr[2 * c + 1]);
    }
    float c_reg = c0[b * H_DIM + j];

    smask[half][l] = 1.0f - done[(size_t)l * B_ENV + b];   // l == t
    if (l < 64) {
        const float sm0 = 1.0f - done[b];
        const float* hp = h0 + b * H_DIM;
        h16[half][0][l] = pack16(hp[2 * l] * sm0, hp[2 * l + 1] * sm0);
    }
    const size_t XSTR = (size_t)B_ENV * G4;
    const unsigned short* xgp = xg + (size_t)b * G4 + (qq * H_DIM + j);
    unsigned short xcur = xgp[0];
    float* hsp = hs + (size_t)b * H_DIM + j;
    __syncthreads();

    float dm = 1.0f - done[b];   // == smask[half][0]

    #pragma unroll 2
    for (int t = 0; t < T_STEPS - 1; ++t) {
        const int rb = t & 1, wb = rb ^ 1;

        // prefetch next step's xg (full-step latency budget)
        xgp += XSTR;
        const unsigned short xnext = xgp[0];

        // ---- k-quarter dots vs h (pre-masked) ----
        const h8v* hp8 = reinterpret_cast<const h8v*>(&h16[half][rb][qq * 16]);
        float s0 = 0.f, s1 = 0.f, s2 = 0.f, s3 = 0.f;
        #pragma unroll
        for (int c4 = 0; c4 < 4; ++c4) {
            union { h8v v; h2v p[4]; } u;
            u.v = hp8[c4];
            #pragma unroll
            for (int pp = 0; pp < 4; ++pp) {
                s0 = dot2(whh[      c4 * 4 + pp], u.p[pp], s0);
                s1 = dot2(whh[16 +  c4 * 4 + pp], u.p[pp], s1);
                s2 = dot2(whh[32 +  c4 * 4 + pp], u.p[pp], s2);
                s3 = dot2(whh[48 +  c4 * 4 + pp], u.p[pp], s3);
            }
        }

        s0 = quad_allreduce(s0);
        s1 = quad_allreduce(s1);
        s2 = quad_allreduce(s2);
        s3 = quad_allreduce(s3);

        // ---- lane qq: own gate (+xg, bias pre-folded), 1 act, broadcast ----
        const float xgf = (float)__builtin_bit_cast(__fp16, xcur);
        const float s01 = (qq & 1) ? s1 : s0;
        const float s23 = (qq & 1) ? s3 : s2;
        const float gs  = ((qq & 2) ? s23 : s01) + xgf;
        const float av  = (qq == 2) ? tanh_f(gs) : sigm(gs);
        const float ai  = dpp_mov<0x00>(av);
        const float af  = dpp_mov<0x55>(av);
        const float ag  = dpp_mov<0xAA>(av);
        const float ao  = dpp_mov<0xFF>(av);

        // ---- cell update, replicated (bit-identical) in quad ----
        const float cn = af * (c_reg * dm) + ai * ag;
        c_reg = cn;
        const float hn = ao * tanh_f(cn);

        const float smn = smask[half][t + 1];
        if (qq == 0) {
            reinterpret_cast<_Float16*>(h16[half][wb])[j] = (_Float16)(hn * smn);
            hsp[0] = hn;   // fire-and-forget
        }
        hsp += (size_t)B_ENV * H_DIM;
        dm   = smn;
        xcur = xnext;
        sync_lds();   // single barrier: h_t published (both envs)
    }

    // ---- peeled last step (t = T-1): no prefetch, no h16 write ----
    {
        const int rb = (T_STEPS - 1) & 1;
        const h8v* hp8 = reinterpret_cast<const h8v*>(&h16[half][rb][qq * 16]);
        float s0 = 0.f, s1 = 0.f, s2 = 0.f, s3 = 0.f;
        #pragma unroll
        for (int c4 = 0; c4 < 4; ++c4) {
            union { h8v v; h2v p[4]; } u;
            u.v = hp8[c4];
            #pragma unroll
            for (int pp = 0; pp < 4; ++pp) {
                s0 = dot2(whh[      c4 * 4 + pp], u.p[pp], s0);
                s1 = dot2(whh[16 +  c4 * 4 + pp], u.p[pp], s1);
                s2 = dot2(whh[32 +  c4 * 4 + pp], u.p[pp], s2);
                s3 = dot2(whh[48 +  c4 * 4 + pp], u.p[pp], s3);
            }
        }
        s0 = quad_allreduce(s0);
        s1 = quad_allreduce(s1);
        s2 = quad_allreduce(s2);
        s3 = quad_allreduce(s3);
        const float xgf = (float)__builtin_bit_cast(__fp16, xcur);
        const float s01 = (qq & 1) ? s1 : s0;
        const float s23 = (qq & 1) ? s3 : s2;
        const float gs  = ((qq & 2) ? s23 : s01) + xgf;
        const float av  = (qq == 2) ? tanh_f(gs) : sigm(gs);
        const float ai  = dpp_mov<0x00>(av);
        const float af  = dpp_mov<0x55>(av);
        const float ag  = dpp_mov<0xAA>(av);
        const float ao  = dpp_mov<0xFF>(av);
        const float cn  = af * (c_reg * dm) + ai * ag;
        const float hn  = ao * tanh_f(cn);
        if (qq == 0) hsp[0] = hn;
    }
}

// ---------------------------------------------------------------------------
// Fallback scan (R14 verbatim): used when ws_size can't hold xg.
__global__ __launch_bounds__(512, 1) __attribute__((amdgpu_waves_per_eu(2, 2)))
void ppo_lstm_scan_fb(const float* __restrict__ x,
                      const float* __restrict__ done,
                      const float* __restrict__ h0,
                      const float* __restrict__ c0,
                      const float* __restrict__ W_ih,
                      const float* __restrict__ b_ih,
                      const float* __restrict__ W_hh,
                      const float* __restrict__ b_hh,
                      float* __restrict__ hs)
{
    const int b   = blockIdx.x;
    const int tid = threadIdx.x;
    const int qq  = tid & 3;
    const int j   = tid >> 2;

    __shared__ alignas(16) h2v   h16[2][H_DIM / 2];
    __shared__ alignas(16) float smask[T_STEPS];

    h2v whh[64];
    h2v wih[32];
    #pragma unroll
    for (int g = 0; g < 4; ++g) {
        const float* wr = W_hh + (size_t)(g * H_DIM + j) * H_DIM + qq * 32;
        #pragma unroll
        for (int c = 0; c < 16; ++c)
            whh[g * 16 + c] = pack16(wr[2 * c], wr[2 * c + 1]);
        const float* wr2 = W_ih + (size_t)(g * H_DIM + j) * D_IN + qq * 16;
        #pragma unroll
        for (int c = 0; c < 8; ++c)
            wih[g * 8 + c] = pack16(wr2[2 * c], wr2[2 * c + 1]);
    }
    const int   r_own    = qq * H_DIM + j;
    const float bias_own = b_ih[r_own] + b_hh[r_own];
    float       c_reg    = c0[b * H_DIM + j];

    smask[tid] = 1.0f - done[(size_t)tid * B_ENV + b];
    if (tid < 64) {
        const float sm0 = 1.0f - done[b];
        const float* hp = h0 + b * H_DIM;
        h16[0][tid] = pack16(hp[2 * tid] * sm0, hp[2 * tid + 1] * sm0);
    }
    f4v xr[4];
    {
        const float* xp = x + (size_t)b * D_IN + qq * 16;
        #pragma unroll
        for (int i = 0; i < 4; ++i)
            xr[i] = *reinterpret_cast<const f4v*>(xp + 4 * i);
    }
    __syncthreads();

    for (int t = 0; t < T_STEPS; ++t) {
        const int rb = t & 1, wb = rb ^ 1;

        h2v xh[8];
        #pragma unroll
        for (int i = 0; i < 4; ++i) {
            xh[2 * i]     = pack16(xr[i].x, xr[i].y);
            xh[2 * i + 1] = pack16(xr[i].z, xr[i].w);
        }
        {
            const int tn = (t + 1 < T_STEPS) ? (t + 1) : t;
            const float* xp = x + ((size_t)tn * B_ENV + b) * D_IN + qq * 16;
            #pragma unroll
            for (int i = 0; i < 4; ++i)
                xr[i] = *reinterpret_cast<const f4v*>(xp + 4 * i);
        }

        const h8v* hp8 = reinterpret_cast<const h8v*>(&h16[rb][qq * 16]);
        float s0 = 0.f, s1 = 0.f, s2 = 0.f, s3 = 0.f;
        #pragma unroll
        for (int c4 = 0; c4 < 4; ++c4) {
            union { h8v v; h2v p[4]; } u;
            u.v = hp8[c4];
            #pragma unroll
            for (int pp = 0; pp < 4; ++pp) {
                s0 = dot2(whh[      c4 * 4 + pp], u.p[pp], s0);
                s1 = dot2(whh[16 +  c4 * 4 + pp], u.p[pp], s1);
                s2 = dot2(whh[32 +  c4 * 4 + pp], u.p[pp], s2);
                s3 = dot2(whh[48 +  c4 * 4 + pp], u.p[pp], s3);
            }
        }
        #pragma unroll
        for (int c = 0; c < 8; ++c) {
            s0 = dot2(wih[     c], xh[c], s0);
            s1 = dot2(wih[ 8 + c], xh[c], s1);
            s2 = dot2(wih[16 + c], xh[c], s2);
            s3 = dot2(wih[24 + c], xh[c], s3);
        }

        s0 = quad_allreduce(s0);
        s1 = quad_allreduce(s1);
        s2 = quad_allreduce(s2);
        s3 = quad_allreduce(s3);

        const float s01 = (qq & 1) ? s1 : s0;
        const float s23 = (qq & 1) ? s3 : s2;
        const float gs  = ((qq & 2) ? s23 : s01) + bias_own;
        const float av  = (qq == 2) ? tanh_f(gs) : sigm(gs);
        const float ai  = dpp_mov<0x00>(av);
        const float af  = dpp_mov<0x55>(av);
        const float ag  = dpp_mov<0xAA>(av);
        const float ao  = dpp_mov<0xFF>(av);

        const float dm = smask[t];
        const float cn = af * (c_reg * dm) + ai * ag;
        c_reg = cn;
        const float hn = ao * tanh_f(cn);

        if (qq == 0) {
            const float smn = smask[(t + 1 < T_STEPS) ? (t + 1) : (T_STEPS - 1)];
            reinterpret_cast<_Float16*>(h16[wb])[j] = (_Float16)(hn * smn);
            hs[((size_t)t * B_ENV + b) * H_DIM + j] = hn;
        }
        sync_lds();
    }
}

// ---------------------------------------------------------------------------
// In-place row projection: out[r,:] = out_row @ W_hid^T + b_hid.
#define PADK 68
__global__ __launch_bounds__(256)
void ppo_proj(const float* __restrict__ W_hid,   // [H,H]
              const float* __restrict__ b_hid,   // [H]
              float* __restrict__ out)           // [T*B, H] in-place
{
    __shared__ h2v wl[H_DIM][PADK];
    __shared__ h2v hl[H_DIM][PADK];
    const int tid = threadIdx.x;
    const int rg  = tid >> 4;
    const int cg  = tid & 15;

    const size_t r0 = (size_t)blockIdx.x * H_DIM;

    #pragma unroll
    for (int i = 0; i < 16; ++i) {
        const int idx = tid + 256 * i;
        const int r = idx >> 5, cc = idx & 31;
        f4v v = *reinterpret_cast<const f4v*>(W_hid + 4 * (size_t)idx);
        wl[r][2 * cc]     = pack16(v.x, v.y);
        wl[r][2 * cc + 1] = pack16(v.z, v.w);
    }
    #pragma unroll
    for (int i = 0; i < 16; ++i) {
        const int idx = tid + 256 * i;
        const int r = idx >> 5, cc = idx & 31;
        f4v v = *reinterpret_cast<const f4v*>(out + (r0 + r) * H_DIM + 4 * cc);
        hl[r][2 * cc]     = pack16(v.x, v.y);
        hl[r][2 * cc + 1] = pack16(v.z, v.w);
    }
    float bcol[8];
    #pragma unroll
    for (int jj = 0; jj < 8; ++jj) bcol[jj] = b_hid[cg + 16 * jj];
    __syncthreads();

    float acc[8][8];
    #pragma unroll
    for (int i = 0; i < 8; ++i)
        #pragma unroll
        for (int jj = 0; jj < 8; ++jj) acc[i][jj] = 0.f;

    for (int kq = 0; kq < 16; ++kq) {
        union { h8v v; h2v p[4]; } hv[8], wv[8];
        #pragma unroll
        for (int i = 0; i < 8; ++i)
            hv[i].v = *reinterpret_cast<const h8v*>(&hl[rg * 8 + i][4 * kq]);
        #pragma unroll
        for (int jj = 0; jj < 8; ++jj)
            wv[jj].v = *reinterpret_cast<const h8v*>(&wl[cg + 16 * jj][4 * kq]);
        #pragma unroll
        for (int i = 0; i < 8; ++i)
            #pragma unroll
            for (int jj = 0; jj < 8; ++jj) {
                acc[i][jj] = dot2(hv[i].p[0], wv[jj].p[0], acc[i][jj]);
                acc[i][jj] = dot2(hv[i].p[1], wv[jj].p[1], acc[i][jj]);
                acc[i][jj] = dot2(hv[i].p[2], wv[jj].p[2], acc[i][jj]);
                acc[i][jj] = dot2(hv[i].p[3], wv[jj].p[3], acc[i][jj]);
            }
    }

    #pragma unroll
    for (int i = 0; i < 8; ++i)
        #pragma unroll
        for (int jj = 0; jj < 8; ++jj)
            out[(r0 + rg * 8 + i) * H_DIM + cg + 16 * jj] = acc[i][jj] + bcol[jj];
}

extern "C" void kernel_launch(void* const* d_in, const int* in_sizes, int n_in,
                              void* d_out, int out_size, void* d_ws, size_t ws_size,
                              hipStream_t stream) {
    const float* x     = (const float*)d_in[0];
    const float* done  = (const float*)d_in[1];
    const float* h0    = (const float*)d_in[2];
    const float* c0    = (const float*)d_in[3];
    const float* W_ih  = (const float*)d_in[4];
    const float* b_ih  = (const float*)d_in[5];
    const float* W_hh  = (const float*)d_in[6];
    const float* b_hh  = (const float*)d_in[7];
    const float* W_hid = (const float*)d_in[8];
    const float* b_hid = (const float*)d_in[9];
    float* out = (float*)d_out;
    (void)n_in; (void)in_sizes; (void)out_size;

    const size_t xg_bytes = (size_t)T_STEPS * B_ENV * G4 * sizeof(unsigned short);
    if (ws_size >= xg_bytes) {
        unsigned short* xg = (unsigned short*)d_ws;
        hipLaunchKernelGGL(ppo_xg, dim3((T_STEPS * B_ENV) / 64), dim3(256), 0, stream,
                           x, W_ih, b_ih, b_hh, xg);
        hipLaunchKernelGGL(ppo_lstm_scan_xg2, dim3(B_ENV / 2), dim3(1024), 0, stream,
                           xg, done, h0, c0, W_hh, out);
    } else {
        hipLaunchKernelGGL(ppo_lstm_scan_fb, dim3(B_ENV), dim3(512), 0, stream,
                           x, done, h0, c0, W_ih, b_ih, W_hh, b_hh, out);
    }
    hipLaunchKernelGGL(ppo_proj, dim3((T_STEPS * B_ENV) / H_DIM), dim3(256), 0, stream,
                       W_hid, b_hid, out);
}

// Round 19
// 425.721 us; speedup vs baseline: 1.3359x; 1.3359x over previous
//
#include <hip/hip_runtime.h>

#define T_STEPS 512
#define B_ENV   256
#define D_IN    64
#define H_DIM   128
#define G4      512   // 4*H gate rows

typedef _Float16 h2v __attribute__((ext_vector_type(2)));
typedef _Float16 h8v __attribute__((ext_vector_type(8)));
typedef float    f4v __attribute__((ext_vector_type(4)));
typedef __fp16   g2  __attribute__((ext_vector_type(2)));
typedef __fp16   g8  __attribute__((ext_vector_type(8)));

__device__ __forceinline__ float dot2(h2v a, h2v b, float c) {
#if __has_builtin(__builtin_amdgcn_fdot2)
    return __builtin_amdgcn_fdot2(a, b, c, false);
#else
    return c + (float)a.x * (float)b.x + (float)a.y * (float)b.y;
#endif
}

__device__ __forceinline__ g2 pack16g(float a, float b) {
#if __has_builtin(__builtin_amdgcn_cvt_pkrtz)
    return __builtin_amdgcn_cvt_pkrtz(a, b);
#else
    g2 p; p.x = (__fp16)a; p.y = (__fp16)b; return p;
#endif
}
__device__ __forceinline__ h2v pack16(float a, float b) {
    union { g2 r; h2v h; } u; u.r = pack16g(a, b); return u.h;
}

__device__ __forceinline__ f4v mfma16(g8 a, g8 b, f4v c) {
    return __builtin_amdgcn_mfma_f32_16x16x32_f16(a, b, c, 0, 0, 0);
}

__device__ __forceinline__ float fast_rcp(float x) {
#if __has_builtin(__builtin_amdgcn_rcpf)
    return __builtin_amdgcn_rcpf(x);
#else
    return 1.0f / x;
#endif
}
__device__ __forceinline__ float sigm(float x)   { return fast_rcp(1.0f + __expf(-x)); }
__device__ __forceinline__ float tanh_f(float x) { float e = __expf(2.0f * x); return 1.0f - 2.0f * fast_rcp(e + 1.0f); }

// DPP quad_perm ops (VALU pipe — never LDS).
template <int CTRL>
__device__ __forceinline__ float dpp_mov(float v) {
    int s = __builtin_amdgcn_update_dpp(
        0, __builtin_bit_cast(int, v), CTRL, 0xF, 0xF, true);
    return __builtin_bit_cast(float, s);
}
__device__ __forceinline__ float quad_allreduce(float v) {
    v += dpp_mov<0xB1>(v);   // quad_perm(1,0,3,2): xor1
    v += dpp_mov<0x4E>(v);   // quad_perm(2,3,0,1): xor2
    return v;
}

// Barrier draining LDS ops only — global loads/stores stay in flight.
__device__ __forceinline__ void sync_lds() {
    asm volatile("s_waitcnt lgkmcnt(0)" ::: "memory");
    __builtin_amdgcn_s_barrier();
    asm volatile("" ::: "memory");
}

// ---------------------------------------------------------------------------
// xg GEMM: xg[tb, r] = x[tb,:] . W_ih[r,:] + b_ih[r] + b_hh[r]  (f16 out).
// Bias folded in via MFMA acc-init. M = T*B (2048 blocks x 64), N=512, K=64.
__global__ __launch_bounds__(256)
void ppo_xg(const float* __restrict__ x,     // [T*B, 64]
            const float* __restrict__ W_ih,  // [512, 64]
            const float* __restrict__ b_ih,  // [512]
            const float* __restrict__ b_hh,  // [512]
            unsigned short* __restrict__ xg) // [T*B, 512] f16 bits
{
    const int tid  = threadIdx.x;
    const int lane = tid & 63;
    const int w    = tid >> 6;
    const int rml  = lane & 15;
    const int colg = lane >> 4;

    __shared__ h2v   wl[G4][36];   // 512 rows x 32 h2v (+4 pad) = 72 KB
    __shared__ float bl[G4];       // bias per gate row (2 KB)

    #pragma unroll
    for (int i = 0; i < 32; ++i) {             // stage W_ih: 8192 f4v
        const int idx = tid + 256 * i;
        const int r = idx >> 4, cc = idx & 15;
        f4v v = *reinterpret_cast<const f4v*>(W_ih + (size_t)idx * 4);
        wl[r][2 * cc]     = pack16(v.x, v.y);
        wl[r][2 * cc + 1] = pack16(v.z, v.w);
    }
    bl[tid]       = b_ih[tid]       + b_hh[tid];
    bl[tid + 256] = b_ih[tid + 256] + b_hh[tid + 256];
    __syncthreads();

    const size_t row0 = (size_t)blockIdx.x * 64 + w * 16;

    // A-frags: 2 K-strips of x rows (lane rml = row, colg = k-group)
    g8 a[2];
    #pragma unroll
    for (int ks = 0; ks < 2; ++ks) {
        const float* p = x + (row0 + rml) * D_IN + ks * 32 + colg * 8;
        union { g2 q[4]; g8 v; } u;
        #pragma unroll
        for (int c = 0; c < 4; ++c) u.q[c] = pack16g(p[2 * c], p[2 * c + 1]);
        a[ks] = u.v;
    }

    #pragma unroll 4
    for (int ct = 0; ct < 32; ++ct) {          // 32 column tiles of 16 gates
        const int col = ct * 16 + rml;         // B col = lane&15 = C col
        const g8 b0 = *reinterpret_cast<const g8*>(&wl[col][colg * 4]);
        const g8 b1 = *reinterpret_cast<const g8*>(&wl[col][16 + colg * 4]);
        const float bb = bl[col];
        f4v acc = {bb, bb, bb, bb};
        acc = mfma16(a[0], b0, acc);
        acc = mfma16(a[1], b1, acc);
        // C: row = colg*4+reg, col = rml
        #pragma unroll
        for (int reg = 0; reg < 4; ++reg) {
            const __fp16 hv = (__fp16)acc[reg];
            xg[(row0 + colg * 4 + reg) * G4 + ct * 16 + rml] =
                __builtin_bit_cast(unsigned short, hv);
        }
    }
}

// ---------------------------------------------------------------------------
// Fused scan+proj: one block per env, 640 threads = 10 waves.
//  Waves 0-7 (tid<512): R15 gate recurrence. Thread (j=tid>>2, qq=tid&3)
//    holds k-quarter qq of gate rows {j,128+j,256+j,384+j} of W_hh (64 h2v).
//    h16 now stores RAW h (unmasked); the done-mask enters via ONE fma:
//    gs = fma(dm, s_own, xg). No global store from gate waves.
//  Waves 8-9 (tid>=512): projection. Thread owns W_hid row pr=tid-512
//    (64 h2v) and computes out[t-1] = h_{t-1}.whid + b_hid during step t —
//    filling the gate waves' stall bubbles. Writes final f32 out directly;
//    the raw-hs HBM round-trip and the separate proj kernel disappear.
// One lgkm-only barrier per step; last iteration peeled; epilogue emits
// out[T-1].
__global__ __launch_bounds__(640, 1) __attribute__((amdgpu_waves_per_eu(2, 2)))
void ppo_lstm_fused(const unsigned short* __restrict__ xg,  // [T,B,4H] f16
                    const float* __restrict__ done,   // [T,B]
                    const float* __restrict__ h0,     // [B,H]
                    const float* __restrict__ c0,     // [B,H]
                    const float* __restrict__ W_hh,   // [4H,H]
                    const float* __restrict__ W_hid,  // [H,H]
                    const float* __restrict__ b_hid,  // [H]
                    float* __restrict__ out)          // [T*B,H] = d_out
{
    const int b   = blockIdx.x;
    const int tid = threadIdx.x;
    const bool is_gate = tid < 512;          // wave-uniform
    const int qq  = tid & 3;
    const int j   = tid >> 2;
    const int pr  = tid - 512;               // proj out-row

    __shared__ alignas(16) h2v   h16[2][H_DIM / 2];  // RAW h f16, dbuf
    __shared__ alignas(16) float smask[T_STEPS];     // 1-done

    h2v w[64];
    float c_reg = 0.f, bias_hid = 0.f;
    if (is_gate) {
        #pragma unroll
        for (int g = 0; g < 4; ++g) {
            const float* wr = W_hh + (size_t)(g * H_DIM + j) * H_DIM + qq * 32;
            #pragma unroll
            for (int c = 0; c < 16; ++c)
                w[g * 16 + c] = pack16(wr[2 * c], wr[2 * c + 1]);
        }
        c_reg = c0[b * H_DIM + j];
    } else {
        const float* wr = W_hid + (size_t)pr * H_DIM;
        #pragma unroll
        for (int c = 0; c < 64; ++c)
            w[c] = pack16(wr[2 * c], wr[2 * c + 1]);
        bias_hid = b_hid[pr];
    }

    if (tid < T_STEPS)
        smask[tid] = 1.0f - done[(size_t)tid * B_ENV + b];
    if (tid < 64) {
        const float* hp = h0 + b * H_DIM;
        h16[0][tid] = pack16(hp[2 * tid], hp[2 * tid + 1]);   // RAW h0
    }
    const size_t XSTR = (size_t)B_ENV * G4;
    const unsigned short* xgp = xg + (size_t)b * G4 + (qq * H_DIM + j);
    unsigned short xcur = is_gate ? xgp[0] : (unsigned short)0;
    float* outp = out + (size_t)b * H_DIM + pr;   // proj store base
    __syncthreads();

    float dm = 1.0f - done[b];   // == smask[0]

    // full-row proj dot vs a h16 buffer (uniform b128 broadcast reads)
    auto proj_dot = [&](const h2v* hbuf) -> float {
        const h8v* hp8 = reinterpret_cast<const h8v*>(hbuf);
        float a0 = 0.f, a1 = 0.f, a2 = 0.f, a3 = 0.f;
        #pragma unroll
        for (int c = 0; c < 16; ++c) {
            union { h8v v; h2v p[4]; } u;
            u.v = hp8[c];
            a0 = dot2(w[4 * c + 0], u.p[0], a0);
            a1 = dot2(w[4 * c + 1], u.p[1], a1);
            a2 = dot2(w[4 * c + 2], u.p[2], a2);
            a3 = dot2(w[4 * c + 3], u.p[3], a3);
        }
        return (a0 + a1) + (a2 + a3);
    };

    for (int t = 0; t < T_STEPS - 1; ++t) {
        const int rb = t & 1, wb = rb ^ 1;

        if (is_gate) {
            // prefetch next step's xg (full-step latency budget)
            xgp += XSTR;
            const unsigned short xnext = xgp[0];

            // k-quarter dots vs RAW h
            const h8v* hp8 = reinterpret_cast<const h8v*>(&h16[rb][qq * 16]);
            float s0 = 0.f, s1 = 0.f, s2 = 0.f, s3 = 0.f;
            #pragma unroll
            for (int c4 = 0; c4 < 4; ++c4) {
                union { h8v v; h2v p[4]; } u;
                u.v = hp8[c4];
                #pragma unroll
                for (int pp = 0; pp < 4; ++pp) {
                    s0 = dot2(w[      c4 * 4 + pp], u.p[pp], s0);
                    s1 = dot2(w[16 +  c4 * 4 + pp], u.p[pp], s1);
                    s2 = dot2(w[32 +  c4 * 4 + pp], u.p[pp], s2);
                    s3 = dot2(w[48 +  c4 * 4 + pp], u.p[pp], s3);
                }
            }
            s0 = quad_allreduce(s0);
            s1 = quad_allreduce(s1);
            s2 = quad_allreduce(s2);
            s3 = quad_allreduce(s3);

            // lane qq: own gate; done-mask folded as ONE fma
            const float xgf = (float)__builtin_bit_cast(__fp16, xcur);
            const float s01 = (qq & 1) ? s1 : s0;
            const float s23 = (qq & 1) ? s3 : s2;
            const float gs  = __builtin_fmaf(dm, (qq & 2) ? s23 : s01, xgf);
            const float av  = (qq == 2) ? tanh_f(gs) : sigm(gs);
            const float ai  = dpp_mov<0x00>(av);
            const float af  = dpp_mov<0x55>(av);
            const float ag  = dpp_mov<0xAA>(av);
            const float ao  = dpp_mov<0xFF>(av);

            const float cn = af * (c_reg * dm) + ai * ag;
            c_reg = cn;
            const float hn = ao * tanh_f(cn);

            if (qq == 0)
                reinterpret_cast<_Float16*>(h16[wb])[j] = (_Float16)hn;  // RAW
            dm   = smask[t + 1];
            xcur = xnext;
        } else if (t >= 1) {
            // out[t-1] from h_{t-1} (raw) — fills gate-wave stall bubbles
            const float po = proj_dot(&h16[rb][0]);
            outp[(size_t)(t - 1) * B_ENV * H_DIM] = po + bias_hid;
        }
        sync_lds();   // h_t published; proj read of h16[rb] complete
    }

    // ---- peeled t = T-1 ----
    {
        const int rb = (T_STEPS - 1) & 1, wb = rb ^ 1;   // rb=1, wb=0
        if (is_gate) {
            const float xgf = (float)__builtin_bit_cast(__fp16, xcur);
            const h8v* hp8 = reinterpret_cast<const h8v*>(&h16[rb][qq * 16]);
            float s0 = 0.f, s1 = 0.f, s2 = 0.f, s3 = 0.f;
            #pragma unroll
            for (int c4 = 0; c4 < 4; ++c4) {
                union { h8v v; h2v p[4]; } u;
                u.v = hp8[c4];
                #pragma unroll
                for (int pp = 0; pp < 4; ++pp) {
                    s0 = dot2(w[      c4 * 4 + pp], u.p[pp], s0);
                    s1 = dot2(w[16 +  c4 * 4 + pp], u.p[pp], s1);
                    s2 = dot2(w[32 +  c4 * 4 + pp], u.p[pp], s2);
                    s3 = dot2(w[48 +  c4 * 4 + pp], u.p[pp], s3);
                }
            }
            s0 = quad_allreduce(s0);
            s1 = quad_allreduce(s1);
            s2 = quad_allreduce(s2);
            s3 = quad_allreduce(s3);
            const float s01 = (qq & 1) ? s1 : s0;
            const float s23 = (qq & 1) ? s3 : s2;
            const float gs  = __builtin_fmaf(dm, (qq & 2) ? s23 : s01, xgf);
            const float av  = (qq == 2) ? tanh_f(gs) : sigm(gs);
            const float ai  = dpp_mov<0x00>(av);
            const float af  = dpp_mov<0x55>(av);
            const float ag  = dpp_mov<0xAA>(av);
            const float ao  = dpp_mov<0xFF>(av);
            const float cn  = af * (c_reg * dm) + ai * ag;
            const float hn  = ao * tanh_f(cn);
            if (qq == 0)
                reinterpret_cast<_Float16*>(h16[wb])[j] = (_Float16)hn;
        } else {
            const float po = proj_dot(&h16[rb][0]);   // h_{T-2}
            outp[(size_t)(T_STEPS - 2) * B_ENV * H_DIM] = po + bias_hid;
        }
        sync_lds();   // h_{T-1} (in h16[0]) published
    }
    if (!is_gate) {
        const float po = proj_dot(&h16[0][0]);        // h_{T-1}
        outp[(size_t)(T_STEPS - 1) * B_ENV * H_DIM] = po + bias_hid;
    }
}

// ---------------------------------------------------------------------------
// Fallback scan (R14 verbatim): used when ws_size can't hold xg.
__global__ __launch_bounds__(512, 1) __attribute__((amdgpu_waves_per_eu(2, 2)))
void ppo_lstm_scan_fb(const float* __restrict__ x,
                      const float* __restrict__ done,
                      const float* __restrict__ h0,
                      const float* __restrict__ c0,
                      const float* __restrict__ W_ih,
                      const float* __restrict__ b_ih,
                      const float* __restrict__ W_hh,
                      const float* __restrict__ b_hh,
                      float* __restrict__ hs)
{
    const int b   = blockIdx.x;
    const int tid = threadIdx.x;
    const int qq  = tid & 3;
    const int j   = tid >> 2;

    __shared__ alignas(16) h2v   h16[2][H_DIM / 2];
    __shared__ alignas(16) float smask[T_STEPS];

    h2v whh[64];
    h2v wih[32];
    #pragma unroll
    for (int g = 0; g < 4; ++g) {
        const float* wr = W_hh + (size_t)(g * H_DIM + j) * H_DIM + qq * 32;
        #pragma unroll
        for (int c = 0; c < 16; ++c)
            whh[g * 16 + c] = pack16(wr[2 * c], wr[2 * c + 1]);
        const float* wr2 = W_ih + (size_t)(g * H_DIM + j) * D_IN + qq * 16;
        #pragma unroll
        for (int c = 0; c < 8; ++c)
            wih[g * 8 + c] = pack16(wr2[2 * c], wr2[2 * c + 1]);
    }
    const int   r_own    = qq * H_DIM + j;
    const float bias_own = b_ih[r_own] + b_hh[r_own];
    float       c_reg    = c0[b * H_DIM + j];

    smask[tid] = 1.0f - done[(size_t)tid * B_ENV + b];
    if (tid < 64) {
        const float sm0 = 1.0f - done[b];
        const float* hp = h0 + b * H_DIM;
        h16[0][tid] = pack16(hp[2 * tid] * sm0, hp[2 * tid + 1] * sm0);
    }
    f4v xr[4];
    {
        const float* xp = x + (size_t)b * D_IN + qq * 16;
        #pragma unroll
        for (int i = 0; i < 4; ++i)
            xr[i] = *reinterpret_cast<const f4v*>(xp + 4 * i);
    }
    __syncthreads();

    for (int t = 0; t < T_STEPS; ++t) {
        const int rb = t & 1, wb = rb ^ 1;

        h2v xh[8];
        #pragma unroll
        for (int i = 0; i < 4; ++i) {
            xh[2 * i]     = pack16(xr[i].x, xr[i].y);
            xh[2 * i + 1] = pack16(xr[i].z, xr[i].w);
        }
        {
            const int tn = (t + 1 < T_STEPS) ? (t + 1) : t;
            const float* xp = x + ((size_t)tn * B_ENV + b) * D_IN + qq * 16;
            #pragma unroll
            for (int i = 0; i < 4; ++i)
                xr[i] = *reinterpret_cast<const f4v*>(xp + 4 * i);
        }

        const h8v* hp8 = reinterpret_cast<const h8v*>(&h16[rb][qq * 16]);
        float s0 = 0.f, s1 = 0.f, s2 = 0.f, s3 = 0.f;
        #pragma unroll
        for (int c4 = 0; c4 < 4; ++c4) {
            union { h8v v; h2v p[4]; } u;
            u.v = hp8[c4];
            #pragma unroll
            for (int pp = 0; pp < 4; ++pp) {
                s0 = dot2(whh[      c4 * 4 + pp], u.p[pp], s0);
                s1 = dot2(whh[16 +  c4 * 4 + pp], u.p[pp], s1);
                s2 = dot2(whh[32 +  c4 * 4 + pp], u.p[pp], s2);
                s3 = dot2(whh[48 +  c4 * 4 + pp], u.p[pp], s3);
            }
        }
        #pragma unroll
        for (int c = 0; c < 8; ++c) {
            s0 = dot2(wih[     c], xh[c], s0);
            s1 = dot2(wih[ 8 + c], xh[c], s1);
            s2 = dot2(wih[16 + c], xh[c], s2);
            s3 = dot2(wih[24 + c], xh[c], s3);
        }

        s0 = quad_allreduce(s0);
        s1 = quad_allreduce(s1);
        s2 = quad_allreduce(s2);
        s3 = quad_allreduce(s3);

        const float s01 = (qq & 1) ? s1 : s0;
        const float s23 = (qq & 1) ? s3 : s2;
        const float gs  = ((qq & 2) ? s23 : s01) + bias_own;
        const float av  = (qq == 2) ? tanh_f(gs) : sigm(gs);
        const float ai  = dpp_mov<0x00>(av);
        const float af  = dpp_mov<0x55>(av);
        const float ag  = dpp_mov<0xAA>(av);
        const float ao  = dpp_mov<0xFF>(av);

        const float dm = smask[t];
        const float cn = af * (c_reg * dm) + ai * ag;
        c_reg = cn;
        const float hn = ao * tanh_f(cn);

        if (qq == 0) {
            const float smn = smask[(t + 1 < T_STEPS) ? (t + 1) : (T_STEPS - 1)];
            reinterpret_cast<_Float16*>(h16[wb])[j] = (_Float16)(hn * smn);
            hs[((size_t)t * B_ENV + b) * H_DIM + j] = hn;
        }
        sync_lds();
    }
}

// ---------------------------------------------------------------------------
// In-place row projection (fallback path only).
#define PADK 68
__global__ __launch_bounds__(256)
void ppo_proj(const float* __restrict__ W_hid,   // [H,H]
              const float* __restrict__ b_hid,   // [H]
              float* __restrict__ out)           // [T*B, H] in-place
{
    __shared__ h2v wl[H_DIM][PADK];
    __shared__ h2v hl[H_DIM][PADK];
    const int tid = threadIdx.x;
    const int rg  = tid >> 4;
    const int cg  = tid & 15;

    const size_t r0 = (size_t)blockIdx.x * H_DIM;

    #pragma unroll
    for (int i = 0; i < 16; ++i) {
        const int idx = tid + 256 * i;
        const int r = idx >> 5, cc = idx & 31;
        f4v v = *reinterpret_cast<const f4v*>(W_hid + 4 * (size_t)idx);
        wl[r][2 * cc]     = pack16(v.x, v.y);
        wl[r][2 * cc + 1] = pack16(v.z, v.w);
    }
    #pragma unroll
    for (int i = 0; i < 16; ++i) {
        const int idx = tid + 256 * i;
        const int r = idx >> 5, cc = idx & 31;
        f4v v = *reinterpret_cast<const f4v*>(out + (r0 + r) * H_DIM + 4 * cc);
        hl[r][2 * cc]     = pack16(v.x, v.y);
        hl[r][2 * cc + 1] = pack16(v.z, v.w);
    }
    float bcol[8];
    #pragma unroll
    for (int jj = 0; jj < 8; ++jj) bcol[jj] = b_hid[cg + 16 * jj];
    __syncthreads();

    float acc[8][8];
    #pragma unroll
    for (int i = 0; i < 8; ++i)
        #pragma unroll
        for (int jj = 0; jj < 8; ++jj) acc[i][jj] = 0.f;

    for (int kq = 0; kq < 16; ++kq) {
        union { h8v v; h2v p[4]; } hv[8], wv[8];
        #pragma unroll
        for (int i = 0; i < 8; ++i)
            hv[i].v = *reinterpret_cast<const h8v*>(&hl[rg * 8 + i][4 * kq]);
        #pragma unroll
        for (int jj = 0; jj < 8; ++jj)
            wv[jj].v = *reinterpret_cast<const h8v*>(&wl[cg + 16 * jj][4 * kq]);
        #pragma unroll
        for (int i = 0; i < 8; ++i)
            #pragma unroll
            for (int jj = 0; jj < 8; ++jj) {
                acc[i][jj] = dot2(hv[i].p[0], wv[jj].p[0], acc[i][jj]);
                acc[i][jj] = dot2(hv[i].p[1], wv[jj].p[1], acc[i][jj]);
                acc[i][jj] = dot2(hv[i].p[2], wv[jj].p[2], acc[i][jj]);
                acc[i][jj] = dot2(hv[i].p[3], wv[jj].p[3], acc[i][jj]);
            }
    }

    #pragma unroll
    for (int i = 0; i < 8; ++i)
        #pragma unroll
        for (int jj = 0; jj < 8; ++jj)
            out[(r0 + rg * 8 + i) * H_DIM + cg + 16 * jj] = acc[i][jj] + bcol[jj];
}

extern "C" void kernel_launch(void* const* d_in, const int* in_sizes, int n_in,
                              void* d_out, int out_size, void* d_ws, size_t ws_size,
                              hipStream_t stream) {
    const float* x     = (const float*)d_in[0];
    const float* done  = (const float*)d_in[1];
    const float* h0    = (const float*)d_in[2];
    const float* c0    = (const float*)d_in[3];
    const float* W_ih  = (const float*)d_in[4];
    const float* b_ih  = (const float*)d_in[5];
    const float* W_hh  = (const float*)d_in[6];
    const float* b_hh  = (const float*)d_in[7];
    const float* W_hid = (const float*)d_in[8];
    const float* b_hid = (const float*)d_in[9];
    float* out = (float*)d_out;
    (void)n_in; (void)in_sizes; (void)out_size;

    const size_t xg_bytes = (size_t)T_STEPS * B_ENV * G4 * sizeof(unsigned short);
    if (ws_size >= xg_bytes) {
        unsigned short* xg = (unsigned short*)d_ws;
        hipLaunchKernelGGL(ppo_xg, dim3((T_STEPS * B_ENV) / 64), dim3(256), 0, stream,
                           x, W_ih, b_ih, b_hh, xg);
        hipLaunchKernelGGL(ppo_lstm_fused, dim3(B_ENV), dim3(640), 0, stream,
                           xg, done, h0, c0, W_hh, W_hid, b_hid, out);
    } else {
        hipLaunchKernelGGL(ppo_lstm_scan_fb, dim3(B_ENV), dim3(512), 0, stream,
                           x, done, h0, c0, W_ih, b_ih, W_hh, b_hh, out);
        hipLaunchKernelGGL(ppo_proj, dim3((T_STEPS * B_ENV) / H_DIM), dim3(256), 0, stream,
                           W_hid, b_hid, out);
    }
}

// Round 20
// 362.017 us; speedup vs baseline: 1.5709x; 1.1760x over previous
//
#include <hip/hip_runtime.h>

#define T_STEPS 512
#define B_ENV   256
#define D_IN    64
#define H_DIM   128
#define G4      512   // 4*H gate rows

typedef _Float16 h2v __attribute__((ext_vector_type(2)));
typedef _Float16 h8v __attribute__((ext_vector_type(8)));
typedef float    f4v __attribute__((ext_vector_type(4)));
typedef __fp16   g2  __attribute__((ext_vector_type(2)));
typedef __fp16   g8  __attribute__((ext_vector_type(8)));

__device__ __forceinline__ float dot2(h2v a, h2v b, float c) {
#if __has_builtin(__builtin_amdgcn_fdot2)
    return __builtin_amdgcn_fdot2(a, b, c, false);
#else
    return c + (float)a.x * (float)b.x + (float)a.y * (float)b.y;
#endif
}

__device__ __forceinline__ g2 pack16g(float a, float b) {
#if __has_builtin(__builtin_amdgcn_cvt_pkrtz)
    return __builtin_amdgcn_cvt_pkrtz(a, b);
#else
    g2 p; p.x = (__fp16)a; p.y = (__fp16)b; return p;
#endif
}
__device__ __forceinline__ h2v pack16(float a, float b) {
    union { g2 r; h2v h; } u; u.r = pack16g(a, b); return u.h;
}

__device__ __forceinline__ f4v mfma16(g8 a, g8 b, f4v c) {
    return __builtin_amdgcn_mfma_f32_16x16x32_f16(a, b, c, 0, 0, 0);
}

__device__ __forceinline__ float fast_rcp(float x) {
#if __has_builtin(__builtin_amdgcn_rcpf)
    return __builtin_amdgcn_rcpf(x);
#else
    return 1.0f / x;
#endif
}
__device__ __forceinline__ float sigm(float x)   { return fast_rcp(1.0f + __expf(-x)); }
__device__ __forceinline__ float tanh_f(float x) { float e = __expf(2.0f * x); return 1.0f - 2.0f * fast_rcp(e + 1.0f); }

// DPP quad_perm ops (VALU pipe — never LDS).
template <int CTRL>
__device__ __forceinline__ float dpp_mov(float v) {
    int s = __builtin_amdgcn_update_dpp(
        0, __builtin_bit_cast(int, v), CTRL, 0xF, 0xF, true);
    return __builtin_bit_cast(float, s);
}
__device__ __forceinline__ float quad_allreduce(float v) {
    v += dpp_mov<0xB1>(v);   // quad_perm(1,0,3,2): xor1
    v += dpp_mov<0x4E>(v);   // quad_perm(2,3,0,1): xor2
    return v;
}

// Barrier draining LDS ops only — global loads/stores stay in flight.
__device__ __forceinline__ void sync_lds() {
    asm volatile("s_waitcnt lgkmcnt(0)" ::: "memory");
    __builtin_amdgcn_s_barrier();
    asm volatile("" ::: "memory");
}

// ---------------------------------------------------------------------------
// xg GEMM: xg[tb, r] = x[tb,:] . W_ih[r,:] + b_ih[r] + b_hh[r]  (f16 out).
// Bias folded in via MFMA acc-init. M = T*B (2048 blocks x 64), N=512, K=64.
__global__ __launch_bounds__(256)
void ppo_xg(const float* __restrict__ x,     // [T*B, 64]
            const float* __restrict__ W_ih,  // [512, 64]
            const float* __restrict__ b_ih,  // [512]
            const float* __restrict__ b_hh,  // [512]
            unsigned short* __restrict__ xg) // [T*B, 512] f16 bits
{
    const int tid  = threadIdx.x;
    const int lane = tid & 63;
    const int w    = tid >> 6;
    const int rml  = lane & 15;
    const int colg = lane >> 4;

    __shared__ h2v   wl[G4][36];   // 512 rows x 32 h2v (+4 pad) = 72 KB
    __shared__ float bl[G4];       // bias per gate row (2 KB)

    #pragma unroll
    for (int i = 0; i < 32; ++i) {             // stage W_ih: 8192 f4v
        const int idx = tid + 256 * i;
        const int r = idx >> 4, cc = idx & 15;
        f4v v = *reinterpret_cast<const f4v*>(W_ih + (size_t)idx * 4);
        wl[r][2 * cc]     = pack16(v.x, v.y);
        wl[r][2 * cc + 1] = pack16(v.z, v.w);
    }
    bl[tid]       = b_ih[tid]       + b_hh[tid];
    bl[tid + 256] = b_ih[tid + 256] + b_hh[tid + 256];
    __syncthreads();

    const size_t row0 = (size_t)blockIdx.x * 64 + w * 16;

    // A-frags: 2 K-strips of x rows (lane rml = row, colg = k-group)
    g8 a[2];
    #pragma unroll
    for (int ks = 0; ks < 2; ++ks) {
        const float* p = x + (row0 + rml) * D_IN + ks * 32 + colg * 8;
        union { g2 q[4]; g8 v; } u;
        #pragma unroll
        for (int c = 0; c < 4; ++c) u.q[c] = pack16g(p[2 * c], p[2 * c + 1]);
        a[ks] = u.v;
    }

    #pragma unroll 4
    for (int ct = 0; ct < 32; ++ct) {          // 32 column tiles of 16 gates
        const int col = ct * 16 + rml;         // B col = lane&15 = C col
        const g8 b0 = *reinterpret_cast<const g8*>(&wl[col][colg * 4]);
        const g8 b1 = *reinterpret_cast<const g8*>(&wl[col][16 + colg * 4]);
        const float bb = bl[col];
        f4v acc = {bb, bb, bb, bb};
        acc = mfma16(a[0], b0, acc);
        acc = mfma16(a[1], b1, acc);
        // C: row = colg*4+reg, col = rml
        #pragma unroll
        for (int reg = 0; reg < 4; ++reg) {
            const __fp16 hv = (__fp16)acc[reg];
            xg[(row0 + colg * 4 + reg) * G4 + ct * 16 + rml] =
                __builtin_bit_cast(unsigned short, hv);
        }
    }
}

// ---------------------------------------------------------------------------
// Scan (R15, best measured: 322 us): one block per env, 512 threads = 8
// waves, ONE lgkm barrier/step. Thread (j=tid>>2, qq=tid&3) owns k-quarter
// qq of gate rows {j,128+j,256+j,384+j} of W_hh (64 h2v). Per step:
// 4 ds_read_b128 (h) -> 64 dot2 -> DPP quad allreduce -> lane qq adds its
// own xg (ONE u16 scalar, prefetched a full step ahead; bias pre-folded),
// activates (lane-specialized), DPP-broadcasts -> replicated cell update ->
// qq==0 writes h16 (pre-scaled by smask[t+1]) + raw h to hs.
// NOTE (R16-R19 post-mortems): all-lane activation, cndmask reduce-scatter,
// >512-thread TLP, and proj fusion each REGRESSED — this loop body is the
// measured local optimum given the compiler's VGPR allocation behavior.
__global__ __launch_bounds__(512, 1) __attribute__((amdgpu_waves_per_eu(2, 2)))
void ppo_lstm_scan_xg(const unsigned short* __restrict__ xg,  // [T,B,4H] f16
                      const float* __restrict__ done,   // [T,B]
                      const float* __restrict__ h0,     // [B,H]
                      const float* __restrict__ c0,     // [B,H]
                      const float* __restrict__ W_hh,   // [4H,H]
                      float* __restrict__ hs)           // [T,B,H] = d_out
{
    const int b   = blockIdx.x;
    const int tid = threadIdx.x;
    const int qq  = tid & 3;
    const int j   = tid >> 2;

    __shared__ alignas(16) h2v   h16[2][H_DIM / 2];  // h f16 (pre-masked), dbuf
    __shared__ alignas(16) float smask[T_STEPS];     // 1-done

    h2v whh[64];   // gate g, k-quarter qq: 16 h2v each
    #pragma unroll
    for (int g = 0; g < 4; ++g) {
        const float* wr = W_hh + (size_t)(g * H_DIM + j) * H_DIM + qq * 32;
        #pragma unroll
        for (int c = 0; c < 16; ++c)
            whh[g * 16 + c] = pack16(wr[2 * c], wr[2 * c + 1]);
    }
    float c_reg = c0[b * H_DIM + j];

    smask[tid] = 1.0f - done[(size_t)tid * B_ENV + b];   // tid == t
    if (tid < 64) {
        const float sm0 = 1.0f - done[b];
        const float* hp = h0 + b * H_DIM;
        h16[0][tid] = pack16(hp[2 * tid] * sm0, hp[2 * tid + 1] * sm0);
    }
    const size_t XSTR = (size_t)B_ENV * G4;
    const unsigned short* xgp = xg + (size_t)b * G4 + (qq * H_DIM + j);
    unsigned short xcur = xgp[0];
    float* hsp = hs + (size_t)b * H_DIM + j;
    __syncthreads();

    float dm = 1.0f - done[b];   // == smask[0]

    #pragma unroll 2
    for (int t = 0; t < T_STEPS - 1; ++t) {
        const int rb = t & 1, wb = rb ^ 1;

        // prefetch next step's xg (full-step latency budget)
        xgp += XSTR;
        const unsigned short xnext = xgp[0];

        // k-quarter dots vs h (pre-masked)
        const h8v* hp8 = reinterpret_cast<const h8v*>(&h16[rb][qq * 16]);
        float s0 = 0.f, s1 = 0.f, s2 = 0.f, s3 = 0.f;
        #pragma unroll
        for (int c4 = 0; c4 < 4; ++c4) {
            union { h8v v; h2v p[4]; } u;
            u.v = hp8[c4];
            #pragma unroll
            for (int pp = 0; pp < 4; ++pp) {
                s0 = dot2(whh[      c4 * 4 + pp], u.p[pp], s0);
                s1 = dot2(whh[16 +  c4 * 4 + pp], u.p[pp], s1);
                s2 = dot2(whh[32 +  c4 * 4 + pp], u.p[pp], s2);
                s3 = dot2(whh[48 +  c4 * 4 + pp], u.p[pp], s3);
            }
        }

        s0 = quad_allreduce(s0);
        s1 = quad_allreduce(s1);
        s2 = quad_allreduce(s2);
        s3 = quad_allreduce(s3);

        // lane qq: own gate = sum + xg (bias pre-folded), 1 act, broadcast
        const float xgf = (float)__builtin_bit_cast(__fp16, xcur);
        const float s01 = (qq & 1) ? s1 : s0;
        const float s23 = (qq & 1) ? s3 : s2;
        const float gs  = ((qq & 2) ? s23 : s01) + xgf;
        const float av  = (qq == 2) ? tanh_f(gs) : sigm(gs);
        const float ai  = dpp_mov<0x00>(av);
        const float af  = dpp_mov<0x55>(av);
        const float ag  = dpp_mov<0xAA>(av);
        const float ao  = dpp_mov<0xFF>(av);

        // cell update, replicated (bit-identical) in quad
        const float cn = af * (c_reg * dm) + ai * ag;
        c_reg = cn;
        const float hn = ao * tanh_f(cn);

        const float smn = smask[t + 1];
        if (qq == 0) {
            reinterpret_cast<_Float16*>(h16[wb])[j] = (_Float16)(hn * smn);
            hsp[0] = hn;   // fire-and-forget
        }
        hsp += (size_t)B_ENV * H_DIM;
        dm   = smn;
        xcur = xnext;
        sync_lds();   // single barrier: h_t published
    }

    // ---- peeled last step (t = T-1): no prefetch, no h16 write ----
    {
        const int rb = (T_STEPS - 1) & 1;
        const float xgf = (float)__builtin_bit_cast(__fp16, xcur);
        const h8v* hp8 = reinterpret_cast<const h8v*>(&h16[rb][qq * 16]);
        float s0 = 0.f, s1 = 0.f, s2 = 0.f, s3 = 0.f;
        #pragma unroll
        for (int c4 = 0; c4 < 4; ++c4) {
            union { h8v v; h2v p[4]; } u;
            u.v = hp8[c4];
            #pragma unroll
            for (int pp = 0; pp < 4; ++pp) {
                s0 = dot2(whh[      c4 * 4 + pp], u.p[pp], s0);
                s1 = dot2(whh[16 +  c4 * 4 + pp], u.p[pp], s1);
                s2 = dot2(whh[32 +  c4 * 4 + pp], u.p[pp], s2);
                s3 = dot2(whh[48 +  c4 * 4 + pp], u.p[pp], s3);
            }
        }
        s0 = quad_allreduce(s0);
        s1 = quad_allreduce(s1);
        s2 = quad_allreduce(s2);
        s3 = quad_allreduce(s3);
        const float s01 = (qq & 1) ? s1 : s0;
        const float s23 = (qq & 1) ? s3 : s2;
        const float gs  = ((qq & 2) ? s23 : s01) + xgf;
        const float av  = (qq == 2) ? tanh_f(gs) : sigm(gs);
        const float ai  = dpp_mov<0x00>(av);
        const float af  = dpp_mov<0x55>(av);
        const float ag  = dpp_mov<0xAA>(av);
        const float ao  = dpp_mov<0xFF>(av);
        const float cn  = af * (c_reg * dm) + ai * ag;
        const float hn  = ao * tanh_f(cn);
        if (qq == 0) hsp[0] = hn;
    }
}

// ---------------------------------------------------------------------------
// Fallback scan (R14 verbatim): used when ws_size can't hold xg.
__global__ __launch_bounds__(512, 1) __attribute__((amdgpu_waves_per_eu(2, 2)))
void ppo_lstm_scan_fb(const float* __restrict__ x,
                      const float* __restrict__ done,
                      const float* __restrict__ h0,
                      const float* __restrict__ c0,
                      const float* __restrict__ W_ih,
                      const float* __restrict__ b_ih,
                      const float* __restrict__ W_hh,
                      const float* __restrict__ b_hh,
                      float* __restrict__ hs)
{
    const int b   = blockIdx.x;
    const int tid = threadIdx.x;
    const int qq  = tid & 3;
    const int j   = tid >> 2;

    __shared__ alignas(16) h2v   h16[2][H_DIM / 2];
    __shared__ alignas(16) float smask[T_STEPS];

    h2v whh[64];
    h2v wih[32];
    #pragma unroll
    for (int g = 0; g < 4; ++g) {
        const float* wr = W_hh + (size_t)(g * H_DIM + j) * H_DIM + qq * 32;
        #pragma unroll
        for (int c = 0; c < 16; ++c)
            whh[g * 16 + c] = pack16(wr[2 * c], wr[2 * c + 1]);
        const float* wr2 = W_ih + (size_t)(g * H_DIM + j) * D_IN + qq * 16;
        #pragma unroll
        for (int c = 0; c < 8; ++c)
            wih[g * 8 + c] = pack16(wr2[2 * c], wr2[2 * c + 1]);
    }
    const int   r_own    = qq * H_DIM + j;
    const float bias_own = b_ih[r_own] + b_hh[r_own];
    float       c_reg    = c0[b * H_DIM + j];

    smask[tid] = 1.0f - done[(size_t)tid * B_ENV + b];
    if (tid < 64) {
        const float sm0 = 1.0f - done[b];
        const float* hp = h0 + b * H_DIM;
        h16[0][tid] = pack16(hp[2 * tid] * sm0, hp[2 * tid + 1] * sm0);
    }
    f4v xr[4];
    {
        const float* xp = x + (size_t)b * D_IN + qq * 16;
        #pragma unroll
        for (int i = 0; i < 4; ++i)
            xr[i] = *reinterpret_cast<const f4v*>(xp + 4 * i);
    }
    __syncthreads();

    for (int t = 0; t < T_STEPS; ++t) {
        const int rb = t & 1, wb = rb ^ 1;

        h2v xh[8];
        #pragma unroll
        for (int i = 0; i < 4; ++i) {
            xh[2 * i]     = pack16(xr[i].x, xr[i].y);
            xh[2 * i + 1] = pack16(xr[i].z, xr[i].w);
        }
        {
            const int tn = (t + 1 < T_STEPS) ? (t + 1) : t;
            const float* xp = x + ((size_t)tn * B_ENV + b) * D_IN + qq * 16;
            #pragma unroll
            for (int i = 0; i < 4; ++i)
                xr[i] = *reinterpret_cast<const f4v*>(xp + 4 * i);
        }

        const h8v* hp8 = reinterpret_cast<const h8v*>(&h16[rb][qq * 16]);
        float s0 = 0.f, s1 = 0.f, s2 = 0.f, s3 = 0.f;
        #pragma unroll
        for (int c4 = 0; c4 < 4; ++c4) {
            union { h8v v; h2v p[4]; } u;
            u.v = hp8[c4];
            #pragma unroll
            for (int pp = 0; pp < 4; ++pp) {
                s0 = dot2(whh[      c4 * 4 + pp], u.p[pp], s0);
                s1 = dot2(whh[16 +  c4 * 4 + pp], u.p[pp], s1);
                s2 = dot2(whh[32 +  c4 * 4 + pp], u.p[pp], s2);
                s3 = dot2(whh[48 +  c4 * 4 + pp], u.p[pp], s3);
            }
        }
        #pragma unroll
        for (int c = 0; c < 8; ++c) {
            s0 = dot2(wih[     c], xh[c], s0);
            s1 = dot2(wih[ 8 + c], xh[c], s1);
            s2 = dot2(wih[16 + c], xh[c], s2);
            s3 = dot2(wih[24 + c], xh[c], s3);
        }

        s0 = quad_allreduce(s0);
        s1 = quad_allreduce(s1);
        s2 = quad_allreduce(s2);
        s3 = quad_allreduce(s3);

        const float s01 = (qq & 1) ? s1 : s0;
        const float s23 = (qq & 1) ? s3 : s2;
        const float gs  = ((qq & 2) ? s23 : s01) + bias_own;
        const float av  = (qq == 2) ? tanh_f(gs) : sigm(gs);
        const float ai  = dpp_mov<0x00>(av);
        const float af  = dpp_mov<0x55>(av);
        const float ag  = dpp_mov<0xAA>(av);
        const float ao  = dpp_mov<0xFF>(av);

        const float dm = smask[t];
        const float cn = af * (c_reg * dm) + ai * ag;
        c_reg = cn;
        const float hn = ao * tanh_f(cn);

        if (qq == 0) {
            const float smn = smask[(t + 1 < T_STEPS) ? (t + 1) : (T_STEPS - 1)];
            reinterpret_cast<_Float16*>(h16[wb])[j] = (_Float16)(hn * smn);
            hs[((size_t)t * B_ENV + b) * H_DIM + j] = hn;
        }
        sync_lds();
    }
}

// ---------------------------------------------------------------------------
// In-place row projection: out[r,:] = out_row @ W_hid^T + b_hid.
#define PADK 68
__global__ __launch_bounds__(256)
void ppo_proj(const float* __restrict__ W_hid,   // [H,H]
              const float* __restrict__ b_hid,   // [H]
              float* __restrict__ out)           // [T*B, H] in-place
{
    __shared__ h2v wl[H_DIM][PADK];
    __shared__ h2v hl[H_DIM][PADK];
    const int tid = threadIdx.x;
    const int rg  = tid >> 4;
    const int cg  = tid & 15;

    const size_t r0 = (size_t)blockIdx.x * H_DIM;

    #pragma unroll
    for (int i = 0; i < 16; ++i) {
        const int idx = tid + 256 * i;
        const int r = idx >> 5, cc = idx & 31;
        f4v v = *reinterpret_cast<const f4v*>(W_hid + 4 * (size_t)idx);
        wl[r][2 * cc]     = pack16(v.x, v.y);
        wl[r][2 * cc + 1] = pack16(v.z, v.w);
    }
    #pragma unroll
    for (int i = 0; i < 16; ++i) {
        const int idx = tid + 256 * i;
        const int r = idx >> 5, cc = idx & 31;
        f4v v = *reinterpret_cast<const f4v*>(out + (r0 + r) * H_DIM + 4 * cc);
        hl[r][2 * cc]     = pack16(v.x, v.y);
        hl[r][2 * cc + 1] = pack16(v.z, v.w);
    }
    float bcol[8];
    #pragma unroll
    for (int jj = 0; jj < 8; ++jj) bcol[jj] = b_hid[cg + 16 * jj];
    __syncthreads();

    float acc[8][8];
    #pragma unroll
    for (int i = 0; i < 8; ++i)
        #pragma unroll
        for (int jj = 0; jj < 8; ++jj) acc[i][jj] = 0.f;

    for (int kq = 0; kq < 16; ++kq) {
        union { h8v v; h2v p[4]; } hv[8], wv[8];
        #pragma unroll
        for (int i = 0; i < 8; ++i)
            hv[i].v = *reinterpret_cast<const h8v*>(&hl[rg * 8 + i][4 * kq]);
        #pragma unroll
        for (int jj = 0; jj < 8; ++jj)
            wv[jj].v = *reinterpret_cast<const h8v*>(&wl[cg + 16 * jj][4 * kq]);
        #pragma unroll
        for (int i = 0; i < 8; ++i)
            #pragma unroll
            for (int jj = 0; jj < 8; ++jj) {
                acc[i][jj] = dot2(hv[i].p[0], wv[jj].p[0], acc[i][jj]);
                acc[i][jj] = dot2(hv[i].p[1], wv[jj].p[1], acc[i][jj]);
                acc[i][jj] = dot2(hv[i].p[2], wv[jj].p[2], acc[i][jj]);
                acc[i][jj] = dot2(hv[i].p[3], wv[jj].p[3], acc[i][jj]);
            }
    }

    #pragma unroll
    for (int i = 0; i < 8; ++i)
        #pragma unroll
        for (int jj = 0; jj < 8; ++jj)
            out[(r0 + rg * 8 + i) * H_DIM + cg + 16 * jj] = acc[i][jj] + bcol[jj];
}

extern "C" void kernel_launch(void* const* d_in, const int* in_sizes, int n_in,
                              void* d_out, int out_size, void* d_ws, size_t ws_size,
                              hipStream_t stream) {
    const float* x     = (const float*)d_in[0];
    const float* done  = (const float*)d_in[1];
    const float* h0    = (const float*)d_in[2];
    const float* c0    = (const float*)d_in[3];
    const float* W_ih  = (const float*)d_in[4];
    const float* b_ih  = (const float*)d_in[5];
    const float* W_hh  = (const float*)d_in[6];
    const float* b_hh  = (const float*)d_in[7];
    const float* W_hid = (const float*)d_in[8];
    const float* b_hid = (const float*)d_in[9];
    float* out = (float*)d_out;
    (void)n_in; (void)in_sizes; (void)out_size;

    const size_t xg_bytes = (size_t)T_STEPS * B_ENV * G4 * sizeof(unsigned short);
    if (ws_size >= xg_bytes) {
        unsigned short* xg = (unsigned short*)d_ws;
        hipLaunchKernelGGL(ppo_xg, dim3((T_STEPS * B_ENV) / 64), dim3(256), 0, stream,
                           x, W_ih, b_ih, b_hh, xg);
        hipLaunchKernelGGL(ppo_lstm_scan_xg, dim3(B_ENV), dim3(512), 0, stream,
                           xg, done, h0, c0, W_hh, out);
    } else {
        hipLaunchKernelGGL(ppo_lstm_scan_fb, dim3(B_ENV), dim3(512), 0, stream,
                           x, done, h0, c0, W_ih, b_ih, W_hh, b_hh, out);
    }
    hipLaunchKernelGGL(ppo_proj, dim3((T_STEPS * B_ENV) / H_DIM), dim3(256), 0, stream,
                       W_hid, b_hid, out);
}